// Round 1
// baseline (884.893 us; speedup 1.0000x reference)
//
#include <hip/hip_runtime.h>

// ---------------------------------------------------------------------------
// GCN 2-layer pipeline:
//   x = concat(emb_node, emb_attri)            [N=110000, 128]
//   h1 = relu(spmm(A, x@W1) + b1)              [N, 128]
//   out = relu(spmm(A, h1@W2) + b2)            [N, 64]
// A given as COO edge list (row, col, val), E = 2,000,000.
// Strategy: build CSR once per call (hist -> scan -> scatter), then
// gather-based aggregation (one wave per row, no float atomics).
// ---------------------------------------------------------------------------

__global__ void hist_kernel(const int* __restrict__ row, int* __restrict__ cnt, int E) {
    int stride = gridDim.x * blockDim.x;
    for (int e = blockIdx.x * blockDim.x + threadIdx.x; e < E; e += stride)
        atomicAdd(&cnt[row[e]], 1);
}

// Single-block exclusive scan of cnt[0..n) -> rowptr[0..n], rowptr[n]=total.
__global__ void scan_kernel(const int* __restrict__ cnt, int* __restrict__ rowptr,
                            int n, int total) {
    __shared__ int sums[1024];
    int t = threadIdx.x;
    int chunk = (n + 1023) >> 10;
    int start = t * chunk;
    int end = min(start + chunk, n);
    int s = 0;
    for (int i = start; i < end; ++i) s += cnt[i];
    sums[t] = s;
    __syncthreads();
    // Hillis-Steele inclusive scan over 1024 partials
    for (int off = 1; off < 1024; off <<= 1) {
        int v = (t >= off) ? sums[t - off] : 0;
        __syncthreads();
        sums[t] += v;
        __syncthreads();
    }
    int run = (t == 0) ? 0 : sums[t - 1];
    for (int i = start; i < end; ++i) { rowptr[i] = run; run += cnt[i]; }
    if (t == 0) rowptr[n] = total;
}

// Scatter edges into CSR slots; (col, val) interleaved as int2 for one 8B load.
__global__ void scatter_kernel(const int* __restrict__ row, const int* __restrict__ col,
                               const float* __restrict__ val, const int* __restrict__ rowptr,
                               int* __restrict__ cursor, int2* __restrict__ csr, int E) {
    int stride = gridDim.x * blockDim.x;
    for (int e = blockIdx.x * blockDim.x + threadIdx.x; e < E; e += stride) {
        int r = row[e];
        int p = rowptr[r] + atomicAdd(&cursor[r], 1);
        csr[p] = make_int2(col[e], __float_as_int(val[e]));
    }
}

// out[M, DOUT] = x[M, 128] @ W[128, DOUT].  x rows 0..na-1 from xa, rest from xb.
// Block: 256 threads, 64 rows/block. Thread (tc=t%16, tr=t/16) computes
// 4 rows x CPT cols.  x tile staged in LDS (padded), W streamed via L1/L2.
template<int DOUT, int CPT>
__global__ __launch_bounds__(256) void gemm_kernel(
        const float* __restrict__ xa, const float* __restrict__ xb, int na,
        const float* __restrict__ W, float* __restrict__ out, int M) {
    __shared__ float sX[64][132];  // pad 132: row stride 4 banks -> <=2-way (free)
    int t = threadIdx.x;
    int row0 = blockIdx.x * 64;

    // Stage 64x128 x-tile: 2048 float4s, 8 per thread, coalesced.
    #pragma unroll
    for (int i = 0; i < 8; ++i) {
        int idx = i * 256 + t;            // 0..2047
        int r = idx >> 5;                 // 0..63
        int c4 = (idx & 31) << 2;         // float col 0,4,...,124
        int gr = row0 + r;
        float4 v = make_float4(0.f, 0.f, 0.f, 0.f);
        if (gr < M) {
            const float* src = (gr < na) ? (xa + (size_t)gr * 128)
                                         : (xb + (size_t)(gr - na) * 128);
            v = *(const float4*)(src + c4);
        }
        *(float4*)(&sX[r][c4]) = v;       // 528B row stride: 16B-aligned
    }
    __syncthreads();

    int tc = t & 15, tr = t >> 4;
    int c0 = tc * CPT, r0 = tr * 4;
    float acc[4][CPT];
    #pragma unroll
    for (int i = 0; i < 4; ++i)
        #pragma unroll
        for (int j = 0; j < CPT; ++j) acc[i][j] = 0.f;

    #pragma unroll 4
    for (int k = 0; k < 128; ++k) {
        float x0 = sX[r0 + 0][k];
        float x1 = sX[r0 + 1][k];
        float x2 = sX[r0 + 2][k];
        float x3 = sX[r0 + 3][k];
        float w[CPT];
        #pragma unroll
        for (int j = 0; j < CPT; j += 4) {
            float4 wv = *(const float4*)(W + (size_t)k * DOUT + c0 + j);
            w[j] = wv.x; w[j + 1] = wv.y; w[j + 2] = wv.z; w[j + 3] = wv.w;
        }
        #pragma unroll
        for (int j = 0; j < CPT; ++j) {
            acc[0][j] = fmaf(x0, w[j], acc[0][j]);
            acc[1][j] = fmaf(x1, w[j], acc[1][j]);
            acc[2][j] = fmaf(x2, w[j], acc[2][j]);
            acc[3][j] = fmaf(x3, w[j], acc[3][j]);
        }
    }

    #pragma unroll
    for (int i = 0; i < 4; ++i) {
        int gr = row0 + r0 + i;
        if (gr < M) {
            #pragma unroll
            for (int j = 0; j < CPT; j += 4) {
                float4 o = make_float4(acc[i][j], acc[i][j + 1], acc[i][j + 2], acc[i][j + 3]);
                *(float4*)(out + (size_t)gr * DOUT + c0 + j) = o;
            }
        }
    }
}

// out[r][:] = relu(bias + sum_j val_j * sup[col_j][:]), one wave per row.
// D=128: float2 per lane (512B coalesced gather). D=64: one float per lane.
template<int D>
__global__ __launch_bounds__(256) void agg_kernel(
        const float* __restrict__ sup, const int* __restrict__ rowptr,
        const int2* __restrict__ csr, const float* __restrict__ bias,
        float* __restrict__ out, int M) {
    int wid = (blockIdx.x * 256 + threadIdx.x) >> 6;  // global wave id = row
    int lane = threadIdx.x & 63;
    if (wid >= M) return;
    int jb = rowptr[wid], je = rowptr[wid + 1];
    if (D == 128) {
        float ax = 0.f, ay = 0.f;
        for (int j = jb; j < je; ++j) {
            int2 cv = csr[j];
            float v = __int_as_float(cv.y);
            float2 s = *(const float2*)(sup + (size_t)cv.x * 128 + lane * 2);
            ax = fmaf(v, s.x, ax);
            ay = fmaf(v, s.y, ay);
        }
        float2 b = *(const float2*)(bias + lane * 2);
        float2 o = make_float2(fmaxf(ax + b.x, 0.f), fmaxf(ay + b.y, 0.f));
        *(float2*)(out + (size_t)wid * 128 + lane * 2) = o;
    } else {
        float a = 0.f;
        for (int j = jb; j < je; ++j) {
            int2 cv = csr[j];
            a = fmaf(__int_as_float(cv.y), sup[(size_t)cv.x * 64 + lane], a);
        }
        out[(size_t)wid * 64 + lane] = fmaxf(a + bias[lane], 0.f);
    }
}

extern "C" void kernel_launch(void* const* d_in, const int* in_sizes, int n_in,
                              void* d_out, int out_size, void* d_ws, size_t ws_size,
                              hipStream_t stream) {
    const int*   ei        = (const int*)d_in[0];     // [2, E] row-major
    const float* vals      = (const float*)d_in[1];   // [E]
    const float* emb_node  = (const float*)d_in[2];   // [NN, 128]
    const float* emb_attri = (const float*)d_in[3];   // [NA, 128]
    const float* W1        = (const float*)d_in[4];   // [128, 128]
    const float* b1        = (const float*)d_in[5];   // [128]
    const float* W2        = (const float*)d_in[6];   // [128, 64]
    const float* b2        = (const float*)d_in[7];   // [64]

    const int E  = in_sizes[1];
    const int NN = in_sizes[2] / 128;
    const int NA = in_sizes[3] / 128;
    const int N  = NN + NA;

    const int* row = ei;
    const int* col = ei + E;

    // Workspace layout (~124 MiB):
    char*  ws   = (char*)d_ws;
    size_t S1   = (size_t)N * 128 * sizeof(float);        // 56.32 MB
    float* sup  = (float*)ws;                             // support1, then support2
    float* h1   = (float*)(ws + S1);                      // relu(agg1 + b1)
    int2*  csr  = (int2*)(ws + 2 * S1);                   // E * 8B
    size_t csrB = (size_t)E * sizeof(int2);
    int* rowptr = (int*)(ws + 2 * S1 + csrB);             // (N+1) ints
    size_t rpB  = (((size_t)(N + 1) * 4) + 511) / 512 * 512;
    int* cnt    = (int*)(ws + 2 * S1 + csrB + rpB);       // N ints (hist, then cursor)

    // --- Build CSR ---
    hipMemsetAsync(cnt, 0, (size_t)N * 4, stream);
    hist_kernel<<<2048, 256, 0, stream>>>(row, cnt, E);
    scan_kernel<<<1, 1024, 0, stream>>>(cnt, rowptr, N, E);
    hipMemsetAsync(cnt, 0, (size_t)N * 4, stream);
    scatter_kernel<<<2048, 256, 0, stream>>>(row, col, vals, rowptr, cnt, csr, E);

    int gblocks = (N + 63) / 64;
    int ablocks = (N + 3) / 4;

    // --- Layer 1 ---
    gemm_kernel<128, 8><<<gblocks, 256, 0, stream>>>(emb_node, emb_attri, NN, W1, sup, N);
    agg_kernel<128><<<ablocks, 256, 0, stream>>>(sup, rowptr, csr, b1, h1, N);

    // --- Layer 2 --- (support2 reuses sup buffer; h1 fully consumed by gemm)
    gemm_kernel<64, 4><<<gblocks, 256, 0, stream>>>(h1, h1, N, W2, sup, N);
    agg_kernel<64><<<ablocks, 256, 0, stream>>>(sup, rowptr, csr, b2, (float*)d_out, N);
}

// Round 2
// 497.075 us; speedup vs baseline: 1.7802x; 1.7802x over previous
//
#include <hip/hip_runtime.h>

// ---------------------------------------------------------------------------
// GCN 2-layer pipeline (fp32 in/out, bf16-staged supports):
//   x = concat(emb_node, emb_attri)            [N=110000, 128]
//   h1 = relu(spmm(A, x@W1) + b1)              [N, 128]  (sup1 staged bf16)
//   out = relu(spmm(A, h1@W2) + b2)            [N, 64]   (sup2 staged bf16)
// CSR built per call: hist -> 3-phase scan -> atomic-cursor scatter.
// Aggregation: one wave per row, edge loop unrolled 4/8 for MLP.
// ---------------------------------------------------------------------------

typedef unsigned int uint;
typedef unsigned short ushort;

__device__ __forceinline__ ushort f2bf(float f) {   // RNE float->bf16
    uint u = __float_as_uint(f);
    u += 0x7fffu + ((u >> 16) & 1u);
    return (ushort)(u >> 16);
}
__device__ __forceinline__ float bflo(uint p) { return __uint_as_float(p << 16); }
__device__ __forceinline__ float bfhi(uint p) { return __uint_as_float(p & 0xffff0000u); }

// ---------------- CSR build ----------------

__global__ void hist_kernel(const int* __restrict__ row, int* __restrict__ cnt, int E) {
    int stride = gridDim.x * blockDim.x;
    for (int e = blockIdx.x * blockDim.x + threadIdx.x; e < E; e += stride)
        atomicAdd(&cnt[row[e]], 1);
}

// Phase A: per-block (1024 entries) sums.
__global__ __launch_bounds__(256) void scan_phaseA(const int* __restrict__ cnt,
                                                   int* __restrict__ blocksum, int n) {
    __shared__ int part[256];
    int t = threadIdx.x;
    int base = blockIdx.x * 1024 + t * 4;
    int4 v = make_int4(0, 0, 0, 0);
    if (base + 3 < n) v = *(const int4*)(cnt + base);
    else { for (int i = 0; i < 4; ++i) if (base + i < n) ((int*)&v)[i] = cnt[base + i]; }
    part[t] = v.x + v.y + v.z + v.w;
    __syncthreads();
    for (int off = 128; off > 0; off >>= 1) {
        if (t < off) part[t] += part[t + off];
        __syncthreads();
    }
    if (t == 0) blocksum[blockIdx.x] = part[0];
}

// Phase B: exclusive scan of block sums (nb <= 1024), one block.
__global__ __launch_bounds__(1024) void scan_phaseB(int* __restrict__ blocksum, int nb) {
    __shared__ int sums[1024];
    int t = threadIdx.x;
    int v = (t < nb) ? blocksum[t] : 0;
    sums[t] = v;
    __syncthreads();
    for (int off = 1; off < 1024; off <<= 1) {
        int u = (t >= off) ? sums[t - off] : 0;
        __syncthreads();
        sums[t] += u;
        __syncthreads();
    }
    if (t < nb) blocksum[t] = sums[t] - v;   // exclusive
}

// Phase C: local exclusive scan + block offset -> rowptr.
__global__ __launch_bounds__(256) void scan_phaseC(const int* __restrict__ cnt,
                                                   const int* __restrict__ blocksum,
                                                   int* __restrict__ rowptr, int n, int total) {
    __shared__ int part[256];
    int t = threadIdx.x;
    int base = blockIdx.x * 1024 + t * 4;
    int4 v = make_int4(0, 0, 0, 0);
    if (base + 3 < n) v = *(const int4*)(cnt + base);
    else { for (int i = 0; i < 4; ++i) if (base + i < n) ((int*)&v)[i] = cnt[base + i]; }
    int s = v.x + v.y + v.z + v.w;
    part[t] = s;
    __syncthreads();
    for (int off = 1; off < 256; off <<= 1) {
        int u = (t >= off) ? part[t - off] : 0;
        __syncthreads();
        part[t] += u;
        __syncthreads();
    }
    int r = part[t] - s + blocksum[blockIdx.x];
    if (base < n)     rowptr[base]     = r;
    r += v.x;
    if (base + 1 < n) rowptr[base + 1] = r;
    r += v.y;
    if (base + 2 < n) rowptr[base + 2] = r;
    r += v.z;
    if (base + 3 < n) rowptr[base + 3] = r;
    if (blockIdx.x == 0 && t == 0) rowptr[n] = total;
}

__global__ void scatter_kernel(const int* __restrict__ row, const int* __restrict__ col,
                               const float* __restrict__ val, const int* __restrict__ rowptr,
                               int* __restrict__ cursor, int2* __restrict__ csr, int E) {
    int stride = gridDim.x * blockDim.x;
    for (int e = blockIdx.x * blockDim.x + threadIdx.x; e < E; e += stride) {
        int r = row[e];
        int p = rowptr[r] + atomicAdd(&cursor[r], 1);
        csr[p] = make_int2(col[e], __float_as_int(val[e]));
    }
}

// ---------------- dense GEMM (fp32 in, bf16 out) ----------------
// out[M, DOUT](bf16) = x[M, 128](fp32) @ W[128, DOUT](fp32).
// Rows 0..na-1 from xa, rest from xb. 64 rows/block, 256 threads.
template<int DOUT, int CPT>
__global__ __launch_bounds__(256) void gemm_kernel(
        const float* __restrict__ xa, const float* __restrict__ xb, int na,
        const float* __restrict__ W, ushort* __restrict__ out, int M) {
    __shared__ float sX[64][132];
    int t = threadIdx.x;
    int row0 = blockIdx.x * 64;

    #pragma unroll
    for (int i = 0; i < 8; ++i) {
        int idx = i * 256 + t;
        int r = idx >> 5;
        int c4 = (idx & 31) << 2;
        int gr = row0 + r;
        float4 v = make_float4(0.f, 0.f, 0.f, 0.f);
        if (gr < M) {
            const float* src = (gr < na) ? (xa + (size_t)gr * 128)
                                         : (xb + (size_t)(gr - na) * 128);
            v = *(const float4*)(src + c4);
        }
        *(float4*)(&sX[r][c4]) = v;
    }
    __syncthreads();

    int tc = t & 15, tr = t >> 4;
    int c0 = tc * CPT, r0 = tr * 4;
    float acc[4][CPT];
    #pragma unroll
    for (int i = 0; i < 4; ++i)
        #pragma unroll
        for (int j = 0; j < CPT; ++j) acc[i][j] = 0.f;

    #pragma unroll 4
    for (int k = 0; k < 128; ++k) {
        float x0 = sX[r0 + 0][k];
        float x1 = sX[r0 + 1][k];
        float x2 = sX[r0 + 2][k];
        float x3 = sX[r0 + 3][k];
        float w[CPT];
        #pragma unroll
        for (int j = 0; j < CPT; j += 4) {
            float4 wv = *(const float4*)(W + (size_t)k * DOUT + c0 + j);
            w[j] = wv.x; w[j + 1] = wv.y; w[j + 2] = wv.z; w[j + 3] = wv.w;
        }
        #pragma unroll
        for (int j = 0; j < CPT; ++j) {
            acc[0][j] = fmaf(x0, w[j], acc[0][j]);
            acc[1][j] = fmaf(x1, w[j], acc[1][j]);
            acc[2][j] = fmaf(x2, w[j], acc[2][j]);
            acc[3][j] = fmaf(x3, w[j], acc[3][j]);
        }
    }

    #pragma unroll
    for (int i = 0; i < 4; ++i) {
        int gr = row0 + r0 + i;
        if (gr < M) {
            uint p[CPT / 2];
            #pragma unroll
            for (int j = 0; j < CPT; j += 2)
                p[j / 2] = (uint)f2bf(acc[i][j]) | ((uint)f2bf(acc[i][j + 1]) << 16);
            if (CPT == 8) {
                *(uint4*)(out + (size_t)gr * DOUT + c0) =
                    make_uint4(p[0], p[1], p[2], p[3]);
            } else {
                *(uint2*)(out + (size_t)gr * DOUT + c0) = make_uint2(p[0], p[1]);
            }
        }
    }
}

// ---------------- aggregation (gather), one wave per row ----------------

// D=128: lane handles 2 cols (one packed uint). Unroll 4 edges for MLP.
__global__ __launch_bounds__(256) void agg_kernel128(
        const ushort* __restrict__ sup, const int* __restrict__ rowptr,
        const int2* __restrict__ csr, const float* __restrict__ bias,
        float* __restrict__ out, int M) {
    int wid = (blockIdx.x * 256 + threadIdx.x) >> 6;
    int lane = threadIdx.x & 63;
    if (wid >= M) return;
    int jb = rowptr[wid], je = rowptr[wid + 1];
    float a0x = 0.f, a0y = 0.f, a1x = 0.f, a1y = 0.f;
    int j = jb;
    for (; j + 4 <= je; j += 4) {
        int2 c0 = csr[j], c1 = csr[j + 1], c2 = csr[j + 2], c3 = csr[j + 3];
        uint s0 = *(const uint*)(sup + ((size_t)c0.x << 7) + (lane << 1));
        uint s1 = *(const uint*)(sup + ((size_t)c1.x << 7) + (lane << 1));
        uint s2 = *(const uint*)(sup + ((size_t)c2.x << 7) + (lane << 1));
        uint s3 = *(const uint*)(sup + ((size_t)c3.x << 7) + (lane << 1));
        float v0 = __int_as_float(c0.y), v1 = __int_as_float(c1.y);
        float v2 = __int_as_float(c2.y), v3 = __int_as_float(c3.y);
        a0x = fmaf(v0, bflo(s0), a0x); a0y = fmaf(v0, bfhi(s0), a0y);
        a1x = fmaf(v1, bflo(s1), a1x); a1y = fmaf(v1, bfhi(s1), a1y);
        a0x = fmaf(v2, bflo(s2), a0x); a0y = fmaf(v2, bfhi(s2), a0y);
        a1x = fmaf(v3, bflo(s3), a1x); a1y = fmaf(v3, bfhi(s3), a1y);
    }
    for (; j < je; ++j) {
        int2 c = csr[j];
        uint s = *(const uint*)(sup + ((size_t)c.x << 7) + (lane << 1));
        float v = __int_as_float(c.y);
        a0x = fmaf(v, bflo(s), a0x); a0y = fmaf(v, bfhi(s), a0y);
    }
    float2 b = *(const float2*)(bias + lane * 2);
    float2 o = make_float2(fmaxf(a0x + a1x + b.x, 0.f), fmaxf(a0y + a1y + b.y, 0.f));
    *(float2*)(out + (size_t)wid * 128 + lane * 2) = o;
}

// D=64: lane handles 1 col (ushort load). Unroll 8 edges for MLP.
__global__ __launch_bounds__(256) void agg_kernel64(
        const ushort* __restrict__ sup, const int* __restrict__ rowptr,
        const int2* __restrict__ csr, const float* __restrict__ bias,
        float* __restrict__ out, int M) {
    int wid = (blockIdx.x * 256 + threadIdx.x) >> 6;
    int lane = threadIdx.x & 63;
    if (wid >= M) return;
    int jb = rowptr[wid], je = rowptr[wid + 1];
    float a0 = 0.f, a1 = 0.f;
    int j = jb;
    for (; j + 8 <= je; j += 8) {
        int2 c[8];
        #pragma unroll
        for (int u = 0; u < 8; ++u) c[u] = csr[j + u];
        float s[8];
        #pragma unroll
        for (int u = 0; u < 8; ++u)
            s[u] = __uint_as_float(((uint)sup[((size_t)c[u].x << 6) + lane]) << 16);
        #pragma unroll
        for (int u = 0; u < 8; ++u) {
            float v = __int_as_float(c[u].y);
            if (u & 1) a1 = fmaf(v, s[u], a1);
            else       a0 = fmaf(v, s[u], a0);
        }
    }
    for (; j < je; ++j) {
        int2 c = csr[j];
        float s = __uint_as_float(((uint)sup[((size_t)c.x << 6) + lane]) << 16);
        a0 = fmaf(__int_as_float(c.y), s, a0);
    }
    out[(size_t)wid * 64 + lane] = fmaxf(a0 + a1 + bias[lane], 0.f);
}

// ---------------- launch ----------------

extern "C" void kernel_launch(void* const* d_in, const int* in_sizes, int n_in,
                              void* d_out, int out_size, void* d_ws, size_t ws_size,
                              hipStream_t stream) {
    const int*   ei        = (const int*)d_in[0];     // [2, E]
    const float* vals      = (const float*)d_in[1];   // [E]
    const float* emb_node  = (const float*)d_in[2];   // [NN, 128]
    const float* emb_attri = (const float*)d_in[3];   // [NA, 128]
    const float* W1        = (const float*)d_in[4];   // [128, 128]
    const float* b1        = (const float*)d_in[5];   // [128]
    const float* W2        = (const float*)d_in[6];   // [128, 64]
    const float* b2        = (const float*)d_in[7];   // [64]

    const int E  = in_sizes[1];
    const int NN = in_sizes[2] / 128;
    const int NA = in_sizes[3] / 128;
    const int N  = NN + NA;

    const int* row = ei;
    const int* col = ei + E;

    // Workspace layout (~101 MiB):
    char*  ws    = (char*)d_ws;
    size_t align512 = 512;
    size_t Ss    = (((size_t)N * 128 * sizeof(ushort)) + align512 - 1) / align512 * align512; // sup bf16
    size_t Sh    = (((size_t)N * 128 * sizeof(float))  + align512 - 1) / align512 * align512; // h1 fp32
    size_t csrB  = (((size_t)E * sizeof(int2))         + align512 - 1) / align512 * align512;
    size_t rpB   = (((size_t)(N + 1) * sizeof(int))    + align512 - 1) / align512 * align512;
    size_t cntB  = (((size_t)N * sizeof(int))          + align512 - 1) / align512 * align512;

    ushort* sup    = (ushort*)ws;                       // support (bf16), reused both layers
    float*  h1     = (float*)(ws + Ss);
    int2*   csr    = (int2*)(ws + Ss + Sh);
    int*    rowptr = (int*)(ws + Ss + Sh + csrB);
    int*    cnt    = (int*)(ws + Ss + Sh + csrB + rpB);
    int*    bsum   = (int*)(ws + Ss + Sh + csrB + rpB + cntB);  // <=1024 ints

    // --- Build CSR ---
    int nb = (N + 1023) / 1024;   // scan blocks (<=1024)
    hipMemsetAsync(cnt, 0, (size_t)N * 4, stream);
    hist_kernel<<<2048, 256, 0, stream>>>(row, cnt, E);
    scan_phaseA<<<nb, 256, 0, stream>>>(cnt, bsum, N);
    scan_phaseB<<<1, 1024, 0, stream>>>(bsum, nb);
    scan_phaseC<<<nb, 256, 0, stream>>>(cnt, bsum, rowptr, N, E);
    hipMemsetAsync(cnt, 0, (size_t)N * 4, stream);
    scatter_kernel<<<2048, 256, 0, stream>>>(row, col, vals, rowptr, cnt, csr, E);

    int gblocks = (N + 63) / 64;
    int ablocks = (N + 3) / 4;

    // --- Layer 1 ---
    gemm_kernel<128, 8><<<gblocks, 256, 0, stream>>>(emb_node, emb_attri, NN, W1, sup, N);
    agg_kernel128<<<ablocks, 256, 0, stream>>>(sup, rowptr, csr, b1, h1, N);

    // --- Layer 2 ---
    gemm_kernel<64, 4><<<gblocks, 256, 0, stream>>>(h1, h1, N, W2, sup, N);
    agg_kernel64<<<ablocks, 256, 0, stream>>>(sup, rowptr, csr, b2, (float*)d_out, N);
}

// Round 3
// 356.086 us; speedup vs baseline: 2.4851x; 1.3959x over previous
//
#include <hip/hip_runtime.h>

// ---------------------------------------------------------------------------
// GCN 2-layer pipeline (fp32 in/out, bf16-staged supports):
//   h1 = relu(spmm(A, x@W1) + b1); out = relu(spmm(A, h1@W2) + b2)
// CSR build via two-level bucket sort (bucket = row>>9):
//   P0 bucket hist -> P0b scan -> P1 bin (LDS counting sort, burst writes)
//   -> P2 per-bucket scatter (LDS row hist/scan/cursors, L2-resident window)
// Aggregation: one wave per row, 8-edge MLP unroll, bf16 support gathers.
// ---------------------------------------------------------------------------

typedef unsigned int uint;
typedef unsigned short ushort;

#define RPB_SHIFT 9
#define RPB 512          // rows per bucket
#define MAXB 256         // max buckets (N <= 131072)
#define CH 4096          // edges per bin-block

__device__ __forceinline__ ushort f2bf(float f) {   // RNE float->bf16
    uint u = __float_as_uint(f);
    u += 0x7fffu + ((u >> 16) & 1u);
    return (ushort)(u >> 16);
}
__device__ __forceinline__ float bflo(uint p) { return __uint_as_float(p << 16); }
__device__ __forceinline__ float bfhi(uint p) { return __uint_as_float(p & 0xffff0000u); }

// ---------------- CSR build ----------------

// P0: per-bucket edge counts (LDS-aggregated).
__global__ __launch_bounds__(256) void bucket_hist(const int* __restrict__ row,
                                                   int* __restrict__ bcnt,
                                                   int E, int nbuckets) {
    __shared__ int h[MAXB];
    int t = threadIdx.x;
    h[t] = 0;
    __syncthreads();
    int stride = gridDim.x * blockDim.x;
    for (int e = blockIdx.x * blockDim.x + t; e < E; e += stride)
        atomicAdd(&h[row[e] >> RPB_SHIFT], 1);
    __syncthreads();
    if (t < nbuckets && h[t] > 0) atomicAdd(&bcnt[t], h[t]);
}

// P0b: exclusive scan of bucket counts; init global cursors; rowptr[N]=E.
__global__ __launch_bounds__(256) void bucket_scan(const int* __restrict__ bcnt,
                                                   int* __restrict__ bbase,
                                                   int* __restrict__ bcur,
                                                   int* __restrict__ rowptr,
                                                   int nbuckets, int N, int E) {
    __shared__ int s[256];
    int t = threadIdx.x;
    int c = (t < nbuckets) ? bcnt[t] : 0;
    s[t] = c;
    __syncthreads();
    for (int off = 1; off < 256; off <<= 1) {
        int v = (t >= off) ? s[t - off] : 0;
        __syncthreads();
        s[t] += v;
        __syncthreads();
    }
    int excl = s[t] - c;
    if (t < nbuckets) { bbase[t] = excl; bcur[t] = excl; }
    if (t == 0) { bbase[nbuckets] = E; rowptr[N] = E; }
}

// P1: stage CH edges in regs, counting-sort by bucket in LDS, reserve global
// space per bucket, write contiguous per-bucket bursts.
__global__ __launch_bounds__(256) void bin_kernel(
        const int* __restrict__ row, const int* __restrict__ col,
        const float* __restrict__ val, int* __restrict__ bcur,
        int* __restrict__ brow, int2* __restrict__ bcolval, int E) {
    __shared__ int ssrow[CH];
    __shared__ int2 scolval[CH];
    __shared__ int hist[MAXB], sc[MAXB], lbase[MAXB], cur[MAXB], gbase[MAXB];
    int t = threadIdx.x;
    int c0 = blockIdx.x * CH;

    hist[t] = 0;
    __syncthreads();

    int rr[16]; int2 rc[16];
    #pragma unroll
    for (int k = 0; k < 16; ++k) {
        int e = c0 + (k << 8) + t;
        if (e < E) {
            rr[k] = row[e];
            rc[k] = make_int2(col[e], __float_as_int(val[e]));
            atomicAdd(&hist[rr[k] >> RPB_SHIFT], 1);
        } else rr[k] = -1;
    }
    __syncthreads();

    int c = hist[t];
    sc[t] = c;
    __syncthreads();
    for (int off = 1; off < 256; off <<= 1) {
        int v = (t >= off) ? sc[t - off] : 0;
        __syncthreads();
        sc[t] += v;
        __syncthreads();
    }
    lbase[t] = sc[t] - c;
    cur[t]   = sc[t] - c;
    __syncthreads();
    int total = sc[255];

    #pragma unroll
    for (int k = 0; k < 16; ++k) {
        if (rr[k] >= 0) {
            int b = rr[k] >> RPB_SHIFT;
            int p = atomicAdd(&cur[b], 1);
            ssrow[p]   = rr[k];
            scolval[p] = rc[k];
        }
    }
    if (c > 0) gbase[t] = atomicAdd(&bcur[t], c);
    __syncthreads();

    for (int i = t; i < total; i += 256) {
        int r = ssrow[i];
        int b = r >> RPB_SHIFT;
        int g = gbase[b] + (i - lbase[b]);
        brow[g]    = r;
        bcolval[g] = scolval[i];
    }
}

// P2: one block per bucket. LDS row-hist -> scan -> rowptr + cursors ->
// scatter (col,val) into this bucket's private CSR window.
__global__ __launch_bounds__(256) void final_scatter(
        const int* __restrict__ bbase, const int* __restrict__ brow,
        const int2* __restrict__ bcolval, int* __restrict__ rowptr,
        int2* __restrict__ csr, int N) {
    __shared__ int h[RPB];
    __shared__ int s[256];
    __shared__ int cur[RPB];
    int b = blockIdx.x;
    int t = threadIdx.x;
    int base = bbase[b], end = bbase[b + 1];
    int row0 = b << RPB_SHIFT;

    h[t] = 0; h[t + 256] = 0;
    __syncthreads();
    for (int i = base + t; i < end; i += 256)
        atomicAdd(&h[brow[i] - row0], 1);
    __syncthreads();

    int a0 = h[2 * t], a1 = h[2 * t + 1];
    s[t] = a0 + a1;
    __syncthreads();
    for (int off = 1; off < 256; off <<= 1) {
        int v = (t >= off) ? s[t - off] : 0;
        __syncthreads();
        s[t] += v;
        __syncthreads();
    }
    int e0 = s[t] - a0 - a1;
    cur[2 * t]     = e0;
    cur[2 * t + 1] = e0 + a0;
    int gr0 = row0 + 2 * t, gr1 = row0 + 2 * t + 1;
    if (gr0 < N) rowptr[gr0] = base + e0;
    if (gr1 < N) rowptr[gr1] = base + e0 + a0;
    __syncthreads();

    for (int i = base + t; i < end; i += 256) {
        int r = brow[i] - row0;
        int p = atomicAdd(&cur[r], 1);
        csr[base + p] = bcolval[i];
    }
}

// ---------------- dense GEMM (fp32 in, bf16 out) ----------------
template<int DOUT, int CPT>
__global__ __launch_bounds__(256) void gemm_kernel(
        const float* __restrict__ xa, const float* __restrict__ xb, int na,
        const float* __restrict__ W, ushort* __restrict__ out, int M) {
    __shared__ float sX[64][132];
    int t = threadIdx.x;
    int row0 = blockIdx.x * 64;

    #pragma unroll
    for (int i = 0; i < 8; ++i) {
        int idx = i * 256 + t;
        int r = idx >> 5;
        int c4 = (idx & 31) << 2;
        int gr = row0 + r;
        float4 v = make_float4(0.f, 0.f, 0.f, 0.f);
        if (gr < M) {
            const float* src = (gr < na) ? (xa + (size_t)gr * 128)
                                         : (xb + (size_t)(gr - na) * 128);
            v = *(const float4*)(src + c4);
        }
        *(float4*)(&sX[r][c4]) = v;
    }
    __syncthreads();

    int tc = t & 15, tr = t >> 4;
    int c0 = tc * CPT, r0 = tr * 4;
    float acc[4][CPT];
    #pragma unroll
    for (int i = 0; i < 4; ++i)
        #pragma unroll
        for (int j = 0; j < CPT; ++j) acc[i][j] = 0.f;

    #pragma unroll 4
    for (int k = 0; k < 128; ++k) {
        float x0 = sX[r0 + 0][k];
        float x1 = sX[r0 + 1][k];
        float x2 = sX[r0 + 2][k];
        float x3 = sX[r0 + 3][k];
        float w[CPT];
        #pragma unroll
        for (int j = 0; j < CPT; j += 4) {
            float4 wv = *(const float4*)(W + (size_t)k * DOUT + c0 + j);
            w[j] = wv.x; w[j + 1] = wv.y; w[j + 2] = wv.z; w[j + 3] = wv.w;
        }
        #pragma unroll
        for (int j = 0; j < CPT; ++j) {
            acc[0][j] = fmaf(x0, w[j], acc[0][j]);
            acc[1][j] = fmaf(x1, w[j], acc[1][j]);
            acc[2][j] = fmaf(x2, w[j], acc[2][j]);
            acc[3][j] = fmaf(x3, w[j], acc[3][j]);
        }
    }

    #pragma unroll
    for (int i = 0; i < 4; ++i) {
        int gr = row0 + r0 + i;
        if (gr < M) {
            uint p[CPT / 2];
            #pragma unroll
            for (int j = 0; j < CPT; j += 2)
                p[j / 2] = (uint)f2bf(acc[i][j]) | ((uint)f2bf(acc[i][j + 1]) << 16);
            if (CPT == 8) {
                *(uint4*)(out + (size_t)gr * DOUT + c0) =
                    make_uint4(p[0], p[1], p[2], p[3]);
            } else {
                *(uint2*)(out + (size_t)gr * DOUT + c0) = make_uint2(p[0], p[1]);
            }
        }
    }
}

// ---------------- aggregation (gather), one wave per row ----------------

__global__ __launch_bounds__(256) void agg_kernel128(
        const ushort* __restrict__ sup, const int* __restrict__ rowptr,
        const int2* __restrict__ csr, const float* __restrict__ bias,
        float* __restrict__ out, int M) {
    int wid = (blockIdx.x * 256 + threadIdx.x) >> 6;
    int lane = threadIdx.x & 63;
    if (wid >= M) return;
    int jb = rowptr[wid], je = rowptr[wid + 1];
    float a0x = 0.f, a0y = 0.f, a1x = 0.f, a1y = 0.f;
    int j = jb;
    for (; j + 8 <= je; j += 8) {
        int2 c[8];
        #pragma unroll
        for (int u = 0; u < 8; ++u) c[u] = csr[j + u];
        uint sv[8];
        #pragma unroll
        for (int u = 0; u < 8; ++u)
            sv[u] = *(const uint*)(sup + ((size_t)c[u].x << 7) + (lane << 1));
        #pragma unroll
        for (int u = 0; u < 8; ++u) {
            float v = __int_as_float(c[u].y);
            if (u & 1) { a1x = fmaf(v, bflo(sv[u]), a1x); a1y = fmaf(v, bfhi(sv[u]), a1y); }
            else       { a0x = fmaf(v, bflo(sv[u]), a0x); a0y = fmaf(v, bfhi(sv[u]), a0y); }
        }
    }
    for (; j < je; ++j) {
        int2 cc = csr[j];
        uint sv = *(const uint*)(sup + ((size_t)cc.x << 7) + (lane << 1));
        float v = __int_as_float(cc.y);
        a0x = fmaf(v, bflo(sv), a0x); a0y = fmaf(v, bfhi(sv), a0y);
    }
    float2 bb = *(const float2*)(bias + lane * 2);
    float2 o = make_float2(fmaxf(a0x + a1x + bb.x, 0.f), fmaxf(a0y + a1y + bb.y, 0.f));
    *(float2*)(out + (size_t)wid * 128 + lane * 2) = o;
}

__global__ __launch_bounds__(256) void agg_kernel64(
        const ushort* __restrict__ sup, const int* __restrict__ rowptr,
        const int2* __restrict__ csr, const float* __restrict__ bias,
        float* __restrict__ out, int M) {
    int wid = (blockIdx.x * 256 + threadIdx.x) >> 6;
    int lane = threadIdx.x & 63;
    if (wid >= M) return;
    int jb = rowptr[wid], je = rowptr[wid + 1];
    float a0 = 0.f, a1 = 0.f;
    int j = jb;
    for (; j + 8 <= je; j += 8) {
        int2 c[8];
        #pragma unroll
        for (int u = 0; u < 8; ++u) c[u] = csr[j + u];
        float s[8];
        #pragma unroll
        for (int u = 0; u < 8; ++u)
            s[u] = __uint_as_float(((uint)sup[((size_t)c[u].x << 6) + lane]) << 16);
        #pragma unroll
        for (int u = 0; u < 8; ++u) {
            float v = __int_as_float(c[u].y);
            if (u & 1) a1 = fmaf(v, s[u], a1);
            else       a0 = fmaf(v, s[u], a0);
        }
    }
    for (; j < je; ++j) {
        int2 c = csr[j];
        float s = __uint_as_float(((uint)sup[((size_t)c.x << 6) + lane]) << 16);
        a0 = fmaf(__int_as_float(c.y), s, a0);
    }
    out[(size_t)wid * 64 + lane] = fmaxf(a0 + a1 + bias[lane], 0.f);
}

// ---------------- launch ----------------

extern "C" void kernel_launch(void* const* d_in, const int* in_sizes, int n_in,
                              void* d_out, int out_size, void* d_ws, size_t ws_size,
                              hipStream_t stream) {
    const int*   ei        = (const int*)d_in[0];     // [2, E]
    const float* vals      = (const float*)d_in[1];   // [E]
    const float* emb_node  = (const float*)d_in[2];   // [NN, 128]
    const float* emb_attri = (const float*)d_in[3];   // [NA, 128]
    const float* W1        = (const float*)d_in[4];   // [128, 128]
    const float* b1        = (const float*)d_in[5];   // [128]
    const float* W2        = (const float*)d_in[6];   // [128, 64]
    const float* b2        = (const float*)d_in[7];   // [64]

    const int E  = in_sizes[1];
    const int NN = in_sizes[2] / 128;
    const int NA = in_sizes[3] / 128;
    const int N  = NN + NA;
    const int nbuckets = (N + RPB - 1) >> RPB_SHIFT;   // <= 256 for N <= 131072

    const int* row = ei;
    const int* col = ei + E;

    // Workspace layout (~101 MiB). brow/bcolval alias h1 (dead until agg1).
    char*  ws   = (char*)d_ws;
    size_t A    = 512;
    size_t Ss   = (((size_t)N * 128 * sizeof(ushort)) + A - 1) / A * A;   // sup bf16
    size_t Sh   = (((size_t)N * 128 * sizeof(float))  + A - 1) / A * A;   // h1 fp32
    size_t csrB = (((size_t)E * sizeof(int2))         + A - 1) / A * A;
    size_t rpB  = (((size_t)(N + 1) * sizeof(int))    + A - 1) / A * A;
    size_t browB = (((size_t)E * sizeof(int)) + A - 1) / A * A;

    ushort* sup    = (ushort*)ws;
    float*  h1     = (float*)(ws + Ss);
    int*    brow   = (int*)(ws + Ss);                    // aliases h1
    int2*   bcolval= (int2*)(ws + Ss + browB);           // aliases h1
    int2*   csr    = (int2*)(ws + Ss + Sh);
    int*    rowptr = (int*)(ws + Ss + Sh + csrB);
    int*    bcnt   = (int*)(ws + Ss + Sh + csrB + rpB);            // 256 ints
    int*    bbase  = bcnt + 256;                                   // 257 ints
    int*    bcur   = bcnt + 256 + 260;                             // 256 ints

    // --- Build CSR (two-level bucket sort) ---
    hipMemsetAsync(bcnt, 0, 256 * sizeof(int), stream);
    bucket_hist<<<512, 256, 0, stream>>>(row, bcnt, E, nbuckets);
    bucket_scan<<<1, 256, 0, stream>>>(bcnt, bbase, bcur, rowptr, nbuckets, N, E);
    bin_kernel<<<(E + CH - 1) / CH, 256, 0, stream>>>(row, col, vals, bcur, brow, bcolval, E);
    final_scatter<<<nbuckets, 256, 0, stream>>>(bbase, brow, bcolval, rowptr, csr, N);

    int gblocks = (N + 63) / 64;
    int ablocks = (N + 3) / 4;

    // --- Layer 1 ---
    gemm_kernel<128, 8><<<gblocks, 256, 0, stream>>>(emb_node, emb_attri, NN, W1, sup, N);
    agg_kernel128<<<ablocks, 256, 0, stream>>>(sup, rowptr, csr, b1, h1, N);

    // --- Layer 2 ---
    gemm_kernel<64, 4><<<gblocks, 256, 0, stream>>>(h1, h1, N, W2, sup, N);
    agg_kernel64<<<ablocks, 256, 0, stream>>>(sup, rowptr, csr, b2, (float*)d_out, N);
}

// Round 4
// 309.845 us; speedup vs baseline: 2.8559x; 1.1492x over previous
//
#include <hip/hip_runtime.h>

// ---------------------------------------------------------------------------
// GCN 2-layer pipeline:
//   h1 = relu(spmm(A, x@W1) + b1); out = relu(spmm(A, h1@W2) + b2)
// CSR build: bucket sort (row>>9) -> per-bucket LDS scatter (L2-resident).
// GEMMs: MFMA bf16 (x, W staged fully in LDS; K=128 resident).
// Aggregation: one wave per row, half-wave (32-lane) gathers, 16 edges in
// flight, bf16 supports; h1 kept in bf16.
// ---------------------------------------------------------------------------

typedef unsigned int uint;
typedef unsigned short ushort;
typedef __attribute__((ext_vector_type(8))) short bf16x8;
typedef __attribute__((ext_vector_type(4))) float f32x4;

#define RPB_SHIFT 9
#define RPB 512          // rows per bucket
#define MAXB 256         // max buckets (N <= 131072)
#define CH 4096          // edges per bin-block

__device__ __forceinline__ ushort f2bf(float f) {   // RNE float->bf16
    uint u = __float_as_uint(f);
    u += 0x7fffu + ((u >> 16) & 1u);
    return (ushort)(u >> 16);
}
__device__ __forceinline__ float bflo(uint p) { return __uint_as_float(p << 16); }
__device__ __forceinline__ float bfhi(uint p) { return __uint_as_float(p & 0xffff0000u); }

// ---------------- CSR build ----------------

__global__ __launch_bounds__(256) void bucket_hist(const int* __restrict__ row,
                                                   int* __restrict__ bcnt,
                                                   int E, int nbuckets) {
    __shared__ int h[MAXB];
    int t = threadIdx.x;
    h[t] = 0;
    __syncthreads();
    int stride = gridDim.x * blockDim.x;
    for (int e = blockIdx.x * blockDim.x + t; e < E; e += stride)
        atomicAdd(&h[row[e] >> RPB_SHIFT], 1);
    __syncthreads();
    if (t < nbuckets && h[t] > 0) atomicAdd(&bcnt[t], h[t]);
}

__global__ __launch_bounds__(256) void bucket_scan(const int* __restrict__ bcnt,
                                                   int* __restrict__ bbase,
                                                   int* __restrict__ bcur,
                                                   int* __restrict__ rowptr,
                                                   int nbuckets, int N, int E) {
    __shared__ int s[256];
    int t = threadIdx.x;
    int c = (t < nbuckets) ? bcnt[t] : 0;
    s[t] = c;
    __syncthreads();
    for (int off = 1; off < 256; off <<= 1) {
        int v = (t >= off) ? s[t - off] : 0;
        __syncthreads();
        s[t] += v;
        __syncthreads();
    }
    int excl = s[t] - c;
    if (t < nbuckets) { bbase[t] = excl; bcur[t] = excl; }
    if (t == 0) { bbase[nbuckets] = E; rowptr[N] = E; }
}

__global__ __launch_bounds__(256) void bin_kernel(
        const int* __restrict__ row, const int* __restrict__ col,
        const float* __restrict__ val, int* __restrict__ bcur,
        int* __restrict__ brow, int2* __restrict__ bcolval, int E) {
    __shared__ int ssrow[CH];
    __shared__ int2 scolval[CH];
    __shared__ int hist[MAXB], sc[MAXB], lbase[MAXB], cur[MAXB], gbase[MAXB];
    int t = threadIdx.x;
    int c0 = blockIdx.x * CH;

    hist[t] = 0;
    __syncthreads();

    int rr[16]; int2 rc[16];
    #pragma unroll
    for (int k = 0; k < 16; ++k) {
        int e = c0 + (k << 8) + t;
        if (e < E) {
            rr[k] = row[e];
            rc[k] = make_int2(col[e], __float_as_int(val[e]));
            atomicAdd(&hist[rr[k] >> RPB_SHIFT], 1);
        } else rr[k] = -1;
    }
    __syncthreads();

    int c = hist[t];
    sc[t] = c;
    __syncthreads();
    for (int off = 1; off < 256; off <<= 1) {
        int v = (t >= off) ? sc[t - off] : 0;
        __syncthreads();
        sc[t] += v;
        __syncthreads();
    }
    lbase[t] = sc[t] - c;
    cur[t]   = sc[t] - c;
    __syncthreads();
    int total = sc[255];

    #pragma unroll
    for (int k = 0; k < 16; ++k) {
        if (rr[k] >= 0) {
            int b = rr[k] >> RPB_SHIFT;
            int p = atomicAdd(&cur[b], 1);
            ssrow[p]   = rr[k];
            scolval[p] = rc[k];
        }
    }
    if (c > 0) gbase[t] = atomicAdd(&bcur[t], c);
    __syncthreads();

    for (int i = t; i < total; i += 256) {
        int r = ssrow[i];
        int b = r >> RPB_SHIFT;
        int g = gbase[b] + (i - lbase[b]);
        brow[g]    = r;
        bcolval[g] = scolval[i];
    }
}

__global__ __launch_bounds__(256) void final_scatter(
        const int* __restrict__ bbase, const int* __restrict__ brow,
        const int2* __restrict__ bcolval, int* __restrict__ rowptr,
        int2* __restrict__ csr, int N) {
    __shared__ int h[RPB];
    __shared__ int s[256];
    __shared__ int cur[RPB];
    int b = blockIdx.x;
    int t = threadIdx.x;
    int base = bbase[b], end = bbase[b + 1];
    int row0 = b << RPB_SHIFT;

    h[t] = 0; h[t + 256] = 0;
    __syncthreads();
    for (int i = base + t; i < end; i += 256)
        atomicAdd(&h[brow[i] - row0], 1);
    __syncthreads();

    int a0 = h[2 * t], a1 = h[2 * t + 1];
    s[t] = a0 + a1;
    __syncthreads();
    for (int off = 1; off < 256; off <<= 1) {
        int v = (t >= off) ? s[t - off] : 0;
        __syncthreads();
        s[t] += v;
        __syncthreads();
    }
    int e0 = s[t] - a0 - a1;
    cur[2 * t]     = e0;
    cur[2 * t + 1] = e0 + a0;
    int gr0 = row0 + 2 * t, gr1 = row0 + 2 * t + 1;
    if (gr0 < N) rowptr[gr0] = base + e0;
    if (gr1 < N) rowptr[gr1] = base + e0 + a0;
    __syncthreads();

    for (int i = base + t; i < end; i += 256) {
        int r = brow[i] - row0;
        int p = atomicAdd(&cur[r], 1);
        csr[base + p] = bcolval[i];
    }
}

// ---------------- weight prep: fp32 [k][n] -> bf16 transposed [n][k] ----------
__global__ __launch_bounds__(256) void prep_wt(const float* __restrict__ W1,
                                               const float* __restrict__ W2,
                                               ushort* __restrict__ Wt1,
                                               ushort* __restrict__ Wt2) {
    int t = threadIdx.x;
    for (int i = t; i < 128 * 128; i += 256) {
        int k = i >> 7, n = i & 127;
        Wt1[n * 128 + k] = f2bf(W1[i]);
    }
    for (int i = t; i < 128 * 64; i += 256) {
        int k = i >> 6, n = i & 63;
        Wt2[n * 128 + k] = f2bf(W2[i]);
    }
}

// ---------------- MFMA GEMM: out[M,DOUT](bf16) = x[M,128] @ W[128,DOUT] ------
// A (x) staged bf16 in LDS [64][136]; B (Wt, [n][k]) staged in LDS [DOUT][136].
// 4 waves; wave w computes rows w*16..w*16+15 x all DOUT cols. K=128 resident:
// 4 MFMA K-steps of 32, no global traffic in the inner loop.
template<int DOUT, bool AB16>
__global__ __launch_bounds__(256) void gemm_mfma(
        const void* __restrict__ xa_, const void* __restrict__ xb_, int na,
        const ushort* __restrict__ Wt, ushort* __restrict__ out, int M) {
    __shared__ ushort sX[64][136];
    __shared__ ushort sW[DOUT][136];
    int t = threadIdx.x;
    int row0 = blockIdx.x * 64;

    // stage W: DOUT*16 uint4s
    #pragma unroll
    for (int i = 0; i < DOUT / 16; ++i) {
        int idx = i * 256 + t;
        int n = idx >> 4, c8 = (idx & 15) << 3;
        *(uint4*)(&sW[n][c8]) = *(const uint4*)(Wt + n * 128 + c8);
    }
    // stage X (64 rows x 128 cols, bf16)
    if (AB16) {
        const ushort* xa = (const ushort*)xa_;
        #pragma unroll
        for (int i = 0; i < 4; ++i) {
            int idx = i * 256 + t;
            int r = idx >> 4, c8 = (idx & 15) << 3;
            int gr = row0 + r;
            uint4 v = make_uint4(0, 0, 0, 0);
            if (gr < M) v = *(const uint4*)(xa + (size_t)gr * 128 + c8);
            *(uint4*)(&sX[r][c8]) = v;
        }
    } else {
        const float* xa = (const float*)xa_;
        const float* xb = (const float*)xb_;
        #pragma unroll
        for (int i = 0; i < 8; ++i) {
            int idx = i * 256 + t;
            int r = idx >> 5, c4 = (idx & 31) << 2;
            int gr = row0 + r;
            float4 v = make_float4(0.f, 0.f, 0.f, 0.f);
            if (gr < M) {
                const float* src = (gr < na) ? (xa + (size_t)gr * 128)
                                             : (xb + (size_t)(gr - na) * 128);
                v = *(const float4*)(src + c4);
            }
            uint2 p;
            p.x = (uint)f2bf(v.x) | ((uint)f2bf(v.y) << 16);
            p.y = (uint)f2bf(v.z) | ((uint)f2bf(v.w) << 16);
            *(uint2*)(&sX[r][c4]) = p;
        }
    }
    __syncthreads();

    int lane = t & 63, w = t >> 6;
    int r0 = w * 16;
    int lrow = lane & 15, lk = (lane >> 4) << 3;
    constexpr int NT = DOUT / 16;
    f32x4 acc[NT];
    #pragma unroll
    for (int n = 0; n < NT; ++n) acc[n] = (f32x4){0.f, 0.f, 0.f, 0.f};

    #pragma unroll
    for (int ks = 0; ks < 4; ++ks) {
        bf16x8 a = *(const bf16x8*)(&sX[r0 + lrow][ks * 32 + lk]);
        #pragma unroll
        for (int n = 0; n < NT; ++n) {
            bf16x8 b = *(const bf16x8*)(&sW[n * 16 + lrow][ks * 32 + lk]);
            acc[n] = __builtin_amdgcn_mfma_f32_16x16x32_bf16(a, b, acc[n], 0, 0, 0);
        }
    }
    __syncthreads();
    // acc -> sX (bf16). D layout: col = lane&15, row = (lane>>4)*4 + reg.
    #pragma unroll
    for (int n = 0; n < NT; ++n)
        #pragma unroll
        for (int r = 0; r < 4; ++r)
            sX[r0 + ((lane >> 4) << 2) + r][n * 16 + lrow] = f2bf(acc[n][r]);
    __syncthreads();
    // coalesced store: 8*DOUT uint4s
    constexpr int CW = DOUT / 8;   // uint4s per row
    #pragma unroll
    for (int i = 0; i < DOUT / 32; ++i) {
        int idx = i * 256 + t;
        int r = idx / CW, c8 = (idx % CW) * 8;
        int gr = row0 + r;
        if (gr < M)
            *(uint4*)(out + (size_t)gr * DOUT + c8) = *(const uint4*)(&sX[r][c8]);
    }
}

// ---------------- aggregation: one wave/row, half-wave gathers ----------------

// D=128: half-wave (32 lanes) per edge, uint2 = 4 cols/lane; 16 edges in flight.
// Output h1 in bf16.
__global__ __launch_bounds__(256) void agg_kernel128(
        const ushort* __restrict__ sup, const int* __restrict__ rowptr,
        const int2* __restrict__ csr, const float* __restrict__ bias,
        ushort* __restrict__ out, int M) {
    int wid = (blockIdx.x * 256 + threadIdx.x) >> 6;
    int lane = threadIdx.x & 63;
    if (wid >= M) return;
    int hl = lane & 31, half = lane >> 5;
    int jb = rowptr[wid], je = rowptr[wid + 1];
    float aA0 = 0.f, aA1 = 0.f, aA2 = 0.f, aA3 = 0.f;
    float aB0 = 0.f, aB1 = 0.f, aB2 = 0.f, aB3 = 0.f;
    int j = jb;
    for (; j + 16 <= je; j += 16) {
        int2 c[8];
        #pragma unroll
        for (int u = 0; u < 8; ++u) c[u] = csr[j + 2 * u + half];
        uint2 g[8];
        #pragma unroll
        for (int u = 0; u < 8; ++u)
            g[u] = *(const uint2*)(sup + ((size_t)c[u].x << 7) + (hl << 2));
        #pragma unroll
        for (int u = 0; u < 8; ++u) {
            float v = __int_as_float(c[u].y);
            if (u & 1) {
                aB0 = fmaf(v, bflo(g[u].x), aB0); aB1 = fmaf(v, bfhi(g[u].x), aB1);
                aB2 = fmaf(v, bflo(g[u].y), aB2); aB3 = fmaf(v, bfhi(g[u].y), aB3);
            } else {
                aA0 = fmaf(v, bflo(g[u].x), aA0); aA1 = fmaf(v, bfhi(g[u].x), aA1);
                aA2 = fmaf(v, bflo(g[u].y), aA2); aA3 = fmaf(v, bfhi(g[u].y), aA3);
            }
        }
    }
    for (; j + 2 <= je; j += 2) {
        int2 c = csr[j + half];
        uint2 g = *(const uint2*)(sup + ((size_t)c.x << 7) + (hl << 2));
        float v = __int_as_float(c.y);
        aA0 = fmaf(v, bflo(g.x), aA0); aA1 = fmaf(v, bfhi(g.x), aA1);
        aA2 = fmaf(v, bflo(g.y), aA2); aA3 = fmaf(v, bfhi(g.y), aA3);
    }
    if (j < je && half == 0) {
        int2 c = csr[j];
        uint2 g = *(const uint2*)(sup + ((size_t)c.x << 7) + (hl << 2));
        float v = __int_as_float(c.y);
        aA0 = fmaf(v, bflo(g.x), aA0); aA1 = fmaf(v, bfhi(g.x), aA1);
        aA2 = fmaf(v, bflo(g.y), aA2); aA3 = fmaf(v, bfhi(g.y), aA3);
    }
    float s0 = aA0 + aB0, s1 = aA1 + aB1, s2 = aA2 + aB2, s3 = aA3 + aB3;
    s0 += __shfl_xor(s0, 32); s1 += __shfl_xor(s1, 32);
    s2 += __shfl_xor(s2, 32); s3 += __shfl_xor(s3, 32);
    if (half == 0) {
        float4 b = *(const float4*)(bias + (hl << 2));
        uint2 p;
        p.x = (uint)f2bf(fmaxf(s0 + b.x, 0.f)) | ((uint)f2bf(fmaxf(s1 + b.y, 0.f)) << 16);
        p.y = (uint)f2bf(fmaxf(s2 + b.z, 0.f)) | ((uint)f2bf(fmaxf(s3 + b.w, 0.f)) << 16);
        *(uint2*)(out + (size_t)wid * 128 + (hl << 2)) = p;
    }
}

// D=64: half-wave per edge, uint = 2 cols/lane; fp32 output (d_out).
__global__ __launch_bounds__(256) void agg_kernel64(
        const ushort* __restrict__ sup, const int* __restrict__ rowptr,
        const int2* __restrict__ csr, const float* __restrict__ bias,
        float* __restrict__ out, int M) {
    int wid = (blockIdx.x * 256 + threadIdx.x) >> 6;
    int lane = threadIdx.x & 63;
    if (wid >= M) return;
    int hl = lane & 31, half = lane >> 5;
    int jb = rowptr[wid], je = rowptr[wid + 1];
    float aA0 = 0.f, aA1 = 0.f, aB0 = 0.f, aB1 = 0.f;
    int j = jb;
    for (; j + 16 <= je; j += 16) {
        int2 c[8];
        #pragma unroll
        for (int u = 0; u < 8; ++u) c[u] = csr[j + 2 * u + half];
        uint g[8];
        #pragma unroll
        for (int u = 0; u < 8; ++u)
            g[u] = *(const uint*)(sup + ((size_t)c[u].x << 6) + (hl << 1));
        #pragma unroll
        for (int u = 0; u < 8; ++u) {
            float v = __int_as_float(c[u].y);
            if (u & 1) { aB0 = fmaf(v, bflo(g[u]), aB0); aB1 = fmaf(v, bfhi(g[u]), aB1); }
            else       { aA0 = fmaf(v, bflo(g[u]), aA0); aA1 = fmaf(v, bfhi(g[u]), aA1); }
        }
    }
    for (; j + 2 <= je; j += 2) {
        int2 c = csr[j + half];
        uint g = *(const uint*)(sup + ((size_t)c.x << 6) + (hl << 1));
        float v = __int_as_float(c.y);
        aA0 = fmaf(v, bflo(g), aA0); aA1 = fmaf(v, bfhi(g), aA1);
    }
    if (j < je && half == 0) {
        int2 c = csr[j];
        uint g = *(const uint*)(sup + ((size_t)c.x << 6) + (hl << 1));
        float v = __int_as_float(c.y);
        aA0 = fmaf(v, bflo(g), aA0); aA1 = fmaf(v, bfhi(g), aA1);
    }
    float s0 = aA0 + aB0, s1 = aA1 + aB1;
    s0 += __shfl_xor(s0, 32); s1 += __shfl_xor(s1, 32);
    if (half == 0) {
        float2 b = *(const float2*)(bias + (hl << 1));
        float2 o = make_float2(fmaxf(s0 + b.x, 0.f), fmaxf(s1 + b.y, 0.f));
        *(float2*)(out + (size_t)wid * 64 + (hl << 1)) = o;
    }
}

// ---------------- launch ----------------

extern "C" void kernel_launch(void* const* d_in, const int* in_sizes, int n_in,
                              void* d_out, int out_size, void* d_ws, size_t ws_size,
                              hipStream_t stream) {
    const int*   ei        = (const int*)d_in[0];     // [2, E]
    const float* vals      = (const float*)d_in[1];   // [E]
    const float* emb_node  = (const float*)d_in[2];   // [NN, 128]
    const float* emb_attri = (const float*)d_in[3];   // [NA, 128]
    const float* W1        = (const float*)d_in[4];   // [128, 128]
    const float* b1        = (const float*)d_in[5];   // [128]
    const float* W2        = (const float*)d_in[6];   // [128, 64]
    const float* b2        = (const float*)d_in[7];   // [64]

    const int E  = in_sizes[1];
    const int NN = in_sizes[2] / 128;
    const int NA = in_sizes[3] / 128;
    const int N  = NN + NA;
    const int nbuckets = (N + RPB - 1) >> RPB_SHIFT;   // <= 256

    const int* row = ei;
    const int* col = ei + E;

    // Workspace layout (~73 MiB). brow/bcolval alias h1 (dead until agg1).
    char*  ws   = (char*)d_ws;
    size_t A    = 512;
    size_t Ss   = (((size_t)N * 128 * sizeof(ushort)) + A - 1) / A * A;   // sup bf16
    size_t Sh   = (((size_t)N * 128 * sizeof(ushort)) + A - 1) / A * A;   // h1 bf16
    size_t csrB = (((size_t)E * sizeof(int2))         + A - 1) / A * A;
    size_t rpB  = (((size_t)(N + 1) * sizeof(int))    + A - 1) / A * A;
    size_t browB = (((size_t)E * sizeof(int)) + A - 1) / A * A;

    ushort* sup    = (ushort*)ws;
    ushort* h1     = (ushort*)(ws + Ss);
    int*    brow   = (int*)(ws + Ss);                    // aliases h1
    int2*   bcolval= (int2*)(ws + Ss + browB);           // aliases h1 (needs 24MB<=28MB)
    int2*   csr    = (int2*)(ws + Ss + Sh);
    int*    rowptr = (int*)(ws + Ss + Sh + csrB);
    int*    bcnt   = (int*)(ws + Ss + Sh + csrB + rpB);            // 256 ints
    int*    bbase  = bcnt + 256;                                   // 257 ints
    int*    bcur   = bcnt + 256 + 260;                             // 256 ints
    ushort* Wt1    = (ushort*)(ws + Ss + Sh + csrB + rpB + 4096);  // 32 KB
    ushort* Wt2    = Wt1 + 128 * 128;                              // 16 KB

    // --- CSR build + weight prep ---
    hipMemsetAsync(bcnt, 0, 256 * sizeof(int), stream);
    prep_wt<<<1, 256, 0, stream>>>(W1, W2, Wt1, Wt2);
    bucket_hist<<<512, 256, 0, stream>>>(row, bcnt, E, nbuckets);
    bucket_scan<<<1, 256, 0, stream>>>(bcnt, bbase, bcur, rowptr, nbuckets, N, E);
    bin_kernel<<<(E + CH - 1) / CH, 256, 0, stream>>>(row, col, vals, bcur, brow, bcolval, E);
    final_scatter<<<nbuckets, 256, 0, stream>>>(bbase, brow, bcolval, rowptr, csr, N);

    int gblocks = (N + 63) / 64;
    int ablocks = (N + 3) / 4;

    // --- Layer 1 ---
    gemm_mfma<128, false><<<gblocks, 256, 0, stream>>>(emb_node, emb_attri, NN, Wt1, sup, N);
    agg_kernel128<<<ablocks, 256, 0, stream>>>(sup, rowptr, csr, b1, h1, N);

    // --- Layer 2 ---
    gemm_mfma<64, true><<<gblocks, 256, 0, stream>>>(h1, h1, N, Wt2, sup, N);
    agg_kernel64<<<ablocks, 256, 0, stream>>>(sup, rowptr, csr, b2, (float*)d_out, N);
}